// Round 5
// baseline (554.510 us; speedup 1.0000x reference)
//
#include <hip/hip_runtime.h>
#include <hip/hip_bf16.h>
#include <math.h>

#define BB 64
#define CC 256
#define TT 32
#define HH 7
#define WW 7
#define HW 49
#define NN 1568          // T*H*W
#define KV 97
#define KN 300
#define DD 512
#define NTOK 392
#define TOTAL (BB*TT*HW) // 100352
#define BCAP 256         // boundary-bin compaction capacity per head

typedef float f32x4 __attribute__((ext_vector_type(4)));
typedef short bf16x8 __attribute__((ext_vector_type(8)));

#define GLDS(g, l) __builtin_amdgcn_global_load_lds(                          \
    (const __attribute__((address_space(1))) void*)(g),                       \
    (__attribute__((address_space(3))) void*)(l), 16, 0, 0)

#define MFMA16(a, b, c) __builtin_amdgcn_mfma_f32_16x16x32_bf16(a, b, c, 0, 0, 0)

// ---------------- cam selection (blocks 0..63 of k_trcam) -------------------
__device__ __forceinline__ int binof(float v) {
    int i = (int)(v * 1024.f);
    return i < 0 ? 0 : (i > 1023 ? 1023 : i);
}

// cam_block computes its own argmax + CAM rows directly from x (per-channel
// fully-contiguous float4 streams), then runs the selection pipeline.
// R5: moved from k_gemm into kernel 1 (only needs x/logits, not xp) so it
// hides under the BW-bound transpose instead of the GEMM.
__device__ void cam_block(int b, int tid, char* smem,
                          const float* __restrict__ x,
                          const float* __restrict__ pv, const float* __restrict__ pn,
                          const float* __restrict__ wpv, const float* __restrict__ wpn,
                          float* __restrict__ cam) {
    float* rv = (float*)smem;                 // 6272 B
    float* rn = (float*)(smem + 6272);        // 6272 B
    int* h = (int*)(smem + 12544);            // 4096 B, packed lo16 v / hi16 n
    int* tsum = (int*)(smem + 16640);         // 1024 B
    float* lval_v = (float*)(smem + 17664);   // 1024 B
    int* lidx_v = (int*)(smem + 18688);       // 1024 B
    float* lval_n = (float*)(smem + 19712);   // 1024 B
    int* lidx_n = (int*)(smem + 20736);       // 1024 B
    float* wred = (float*)(smem + 21760);     // 64 B  [wave][4]
    int* sc = (int*)(smem + 21824);           // 6 ints
    float* wvs = (float*)(smem + 21888);      // 1024 B
    float* wns = (float*)(smem + 22912);      // 1024 B
    int* cls2 = (int*)(smem + 23936);         // 8 B

    int lane = tid & 63;
    if (tid < 128) {
        int head = tid >> 6;
        const float* r = head ? (pn + b * KN) : (pv + b * KV);
        int K = head ? KN : KV;
        float best = -1e30f; int bi = 0x7fffffff;
        for (int k = lane; k < K; k += 64) {
            float v = r[k];
            if (v > best || (v == best && k < bi)) { best = v; bi = k; }
        }
        #pragma unroll
        for (int off = 32; off >= 1; off >>= 1) {
            float ov = __shfl_xor(best, off);
            int oi = __shfl_xor(bi, off);
            if (ov > best || (ov == best && oi < bi)) { best = ov; bi = oi; }
        }
        if (lane == 0) cls2[head] = bi;
    }
    __syncthreads();
    wvs[tid] = wpv[cls2[0] * CC + tid];
    wns[tid] = wpn[cls2[1] * CC + tid];
    __syncthreads();

    {
        const f32x4* xb4 = (const f32x4*)(x + (size_t)b * CC * NN);
        bool two = tid < (392 - 256);
        f32x4 av0 = {0.f,0.f,0.f,0.f}, an0 = {0.f,0.f,0.f,0.f};
        f32x4 av1 = {0.f,0.f,0.f,0.f}, an1 = {0.f,0.f,0.f,0.f};
        for (int c = 0; c < CC; ++c) {
            float wv = wvs[c], wn = wns[c];
            const f32x4* rowc = xb4 + (size_t)c * 392;
            f32x4 u0 = rowc[tid];
            #pragma unroll
            for (int r = 0; r < 4; ++r) {
                av0[r] = fmaf(wv, u0[r], av0[r]);
                an0[r] = fmaf(wn, u0[r], an0[r]);
            }
            if (two) {
                f32x4 u1 = rowc[tid + 256];
                #pragma unroll
                for (int r = 0; r < 4; ++r) {
                    av1[r] = fmaf(wv, u1[r], av1[r]);
                    an1[r] = fmaf(wn, u1[r], an1[r]);
                }
            }
        }
        *reinterpret_cast<f32x4*>(rv + 4 * tid) = av0;
        *reinterpret_cast<f32x4*>(rn + 4 * tid) = an0;
        if (two) {
            *reinterpret_cast<f32x4*>(rv + 4 * (tid + 256)) = av1;
            *reinterpret_cast<f32x4*>(rn + 4 * (tid + 256)) = an1;
        }
    }
    __syncthreads();

    float mnv = 1e30f, mxv = -1e30f, mnn = 1e30f, mxn = -1e30f;
    for (int n = tid; n < NN; n += 256) {
        float v = rv[n]; mnv = fminf(mnv, v); mxv = fmaxf(mxv, v);
        float u = rn[n]; mnn = fminf(mnn, u); mxn = fmaxf(mxn, u);
    }
    #pragma unroll
    for (int off = 32; off >= 1; off >>= 1) {
        mnv = fminf(mnv, __shfl_xor(mnv, off));
        mxv = fmaxf(mxv, __shfl_xor(mxv, off));
        mnn = fminf(mnn, __shfl_xor(mnn, off));
        mxn = fmaxf(mxn, __shfl_xor(mxn, off));
    }
    if ((tid & 63) == 0) {
        int wid = tid >> 6;
        wred[wid * 4 + 0] = mnv; wred[wid * 4 + 1] = mxv;
        wred[wid * 4 + 2] = mnn; wred[wid * 4 + 3] = mxn;
    }
    if (tid == 0) { sc[0] = 0; sc[1] = 0; }
    __syncthreads();
    mnv = fminf(fminf(wred[0], wred[4]), fminf(wred[8], wred[12]));
    mxv = fmaxf(fmaxf(wred[1], wred[5]), fmaxf(wred[9], wred[13]));
    mnn = fminf(fminf(wred[2], wred[6]), fminf(wred[10], wred[14]));
    mxn = fmaxf(fmaxf(wred[3], wred[7]), fmaxf(wred[11], wred[15]));
    float iv = 1.f / (mxv - mnv), inn = 1.f / (mxn - mnn);

    for (int n = tid; n < NN; n += 256) {
        rv[n] = (rv[n] - mnv) * iv;
        rn[n] = (rn[n] - mnn) * inn;
    }
    for (int i = tid; i < 1024; i += 256) h[i] = 0;
    __syncthreads();
    for (int n = tid; n < NN; n += 256) {
        atomicAdd(&h[binof(rv[n])], 1);
        atomicAdd(&h[binof(rn[n])], 1 << 16);
    }
    __syncthreads();

    int h0 = h[4 * tid], h1 = h[4 * tid + 1], h2 = h[4 * tid + 2], h3 = h[4 * tid + 3];
    tsum[tid] = h0 + h1 + h2 + h3;
    __syncthreads();
    for (int off = 1; off < 256; off <<= 1) {
        int add = (tid + off < 256) ? tsum[tid + off] : 0;
        __syncthreads();
        tsum[tid] += add;
        __syncthreads();
    }
    {
        int scur = tsum[tid];
        int hk[4] = {h0, h1, h2, h3};
        #pragma unroll
        for (int k = 0; k < 4; ++k) {
            int snext = scur - hk[k];
            int scv = scur & 0xffff, ncv = snext & 0xffff;
            int sh = scur >> 16, nh = snext >> 16;
            if (scv >= NTOK && ncv < NTOK) { sc[2] = 4 * tid + k; sc[3] = ncv; }
            if (sh >= NTOK && nh < NTOK) { sc[4] = 4 * tid + k; sc[5] = nh; }
            scur = snext;
        }
    }
    __syncthreads();
    int bsv = sc[2], abv = sc[3], bsn = sc[4], abn = sc[5];

    for (int n = tid; n < NN; n += 256) {
        float v = rv[n]; int bv = binof(v);
        if (bv < bsv) rv[n] = 0.f;
        else if (bv == bsv) {
            int s = atomicAdd(&sc[0], 1);
            if (s < BCAP) { lval_v[s] = v; lidx_v[s] = n; }
        }
        float u = rn[n]; int bu = binof(u);
        if (bu < bsn) rn[n] = 0.f;
        else if (bu == bsn) {
            int s = atomicAdd(&sc[1], 1);
            if (s < BCAP) { lval_n[s] = u; lidx_n[s] = n; }
        }
    }
    __syncthreads();
    int Lv = sc[0] < BCAP ? sc[0] : BCAP;
    int Ln = sc[1] < BCAP ? sc[1] : BCAP;
    for (int i = tid; i < Lv; i += 256) {
        float vi = lval_v[i]; int ni = lidx_v[i]; int r = 0;
        for (int j = 0; j < Lv; ++j) {
            float vj = lval_v[j]; int nj = lidx_v[j];
            r += (vj > vi || (vj == vi && nj < ni)) ? 1 : 0;
        }
        rv[ni] = (r < NTOK - abv) ? vi : 0.f;
    }
    for (int i = tid; i < Ln; i += 256) {
        float vi = lval_n[i]; int ni = lidx_n[i]; int r = 0;
        for (int j = 0; j < Ln; ++j) {
            float vj = lval_n[j]; int nj = lidx_n[j];
            r += (vj > vi || (vj == vi && nj < ni)) ? 1 : 0;
        }
        rn[ni] = (r < NTOK - abn) ? vi : 0.f;
    }
    __syncthreads();
    for (int n = tid; n < NN; n += 256) cam[b * NN + n] = fmaxf(rv[n], rn[n]);
}

// ---------------- K1: cam (blocks 0..63) + transpose (blocks 64..1087) ------
// Transpose body = R4-proven: block = (b, 2-frame chunk); thread owns channel
// c=tid (98 contiguous floats); writes 82,944 B fully contiguous per block.
__global__ __launch_bounds__(256, 3) void k_trcam(
        const float* __restrict__ x, __hip_bfloat16* __restrict__ xp,
        const float* __restrict__ cw, __hip_bfloat16* __restrict__ wb,
        const float* __restrict__ pv, const float* __restrict__ pn,
        const float* __restrict__ wpv, const float* __restrict__ wpn,
        float* __restrict__ cam, int* __restrict__ counter) {
    __shared__ char smem[50176];
    int bid0 = blockIdx.x;              // 0..1087
    int tid = threadIdx.x;              // 0..255
    if (bid0 < 64) { cam_block(bid0, tid, smem, x, pv, pn, wpv, wpn, cam); return; }
    int bid = bid0 - 64;                // 0..1023
    unsigned short* xs = (unsigned short*)smem;   // [98][256] bf16
    if (bid == 0 && tid == 0) *counter = 0;   // k_bce completion counter

    // wb slice: elements [bid*1152, bid*1152+1152)
    {
        int base = bid * 1152;
        #pragma unroll
        for (int r = 0; r < 5; ++r) {
            int o = base + r * 256 + tid;
            if (o < base + 1152) {
                int kk = o / (DD * CC);
                int rem = o - kk * (DD * CC);
                int d = rem >> 8, c = rem & 255;
                wb[o] = __float2bfloat16(cw[(d * CC + c) * 9 + kk]);
            }
        }
    }

    int b  = bid >> 4;          // 0..63
    int tp = bid & 15;          // 0..15  frame-pair
    int t0 = tp << 1;

    const float2* src = (const float2*)(x + ((size_t)(b * CC + tid) * TT + t0) * HW);
    #pragma unroll 1
    for (int r = 0; r < 6; ++r) {
        float2 v[8];
        #pragma unroll
        for (int j = 0; j < 8; ++j) v[j] = src[r * 8 + j];
        #pragma unroll
        for (int j = 0; j < 8; ++j) {
            int q = (r * 8 + j) * 2;
            __hip_bfloat16 b0 = __float2bfloat16(v[j].x);
            __hip_bfloat16 b1 = __float2bfloat16(v[j].y);
            xs[q * 256 + tid] = *reinterpret_cast<unsigned short*>(&b0);
            xs[(q + 1) * 256 + tid] = *reinterpret_cast<unsigned short*>(&b1);
        }
    }
    {
        float2 v = src[48];
        __hip_bfloat16 b0 = __float2bfloat16(v.x);
        __hip_bfloat16 b1 = __float2bfloat16(v.y);
        xs[96 * 256 + tid] = *reinterpret_cast<unsigned short*>(&b0);
        xs[97 * 256 + tid] = *reinterpret_cast<unsigned short*>(&b1);
    }
    __syncthreads();

    __hip_bfloat16* xpb = xp + (size_t)(b * TT + t0) * 81 * 256;
    const bf16x8 zero = (bf16x8){0, 0, 0, 0, 0, 0, 0, 0};
    for (int u = tid; u < 5184; u += 256) {
        int pos = u >> 5, c0 = (u & 31) * 8;
        int f = pos / 81, p = pos - f * 81;
        int hh = p / 9, ww = p - (p / 9) * 9;
        bf16x8 val = zero;
        if (hh >= 1 && hh <= 7 && ww >= 1 && ww <= 7) {
            int q = f * 49 + (hh - 1) * 7 + (ww - 1);
            val = *reinterpret_cast<const bf16x8*>(xs + q * 256 + c0);
        }
        *reinterpret_cast<bf16x8*>(xpb + (size_t)u * 8) = val;
    }
}

// ---------------- K5: 8-phase-style counted-vmcnt MFMA GEMM -----------------
// R5: BM=256 BN=128 BK=64, 512 thr (8 waves, 4Mx2N, 64x64/wave). 3 tile
// buffers (48 KB each, 144 KB LDS, 1 block/CU), prefetch distance 2 tiles,
// end-of-step s_waitcnt vmcnt(6) -- NEVER vmcnt(0) in the main loop (T4).
// 4 phases/step: {ds_read frag-half || stage 2 GLDS of tile s+2 -> s_barrier
// -> lgkmcnt(0)+sched_barrier -> setprio(1) 8 MFMA setprio(0)} (T3+T5).
// Store/read LDS swizzle identical to the R4-proven kernel (T2).
// K-accumulation order per acc element unchanged -> pl bit-identical.
__global__ __launch_bounds__(512, 2) void k_gemm8(
        const __hip_bfloat16* __restrict__ xp, const __hip_bfloat16* __restrict__ wb,
        const float* __restrict__ convb, const float* __restrict__ scorew,
        float* __restrict__ pl) {
    __shared__ char smem[147456];       // 3 x (A 32K + B 16K)
    int tid = threadIdx.x;              // 0..511
    int bid = blockIdx.x;               // 0..1567 (= 8 x 196)
    int xcd = bid & 7;
    int local = bid >> 3;               // 0..195
    int mtile = xcd * 49 + (local >> 2);
    int nblk = local & 3;
    int m0 = mtile * 256;
    int n0 = nblk * 128;
    int lane = tid & 63, wv = tid >> 6; // 8 waves
    int wm = wv >> 1, wn = wv & 1;      // 4M x 2N
    int ln = lane & 15, qd = lane >> 4;
    int swz = ln & 7;

    // staging geometry: thread -> (row = q*64 + tid>>3, seg = tid&7),
    // source pre-swizzled: seg' = seg ^ (row&7)  (matches read-side XOR).
    int srow = tid >> 3, sseg = tid & 7;
    int swseg = (sseg ^ (srow & 7)) * 8;      // element offset in 64-ch row
    unsigned aoff[4];
    #pragma unroll
    for (int q = 0; q < 4; ++q) {
        int m = m0 + q * 64 + srow;
        int bt = m / HW, qq = m - bt * HW;
        int hh = qq / WW, ww = qq - (qq / WW) * WW;
        aoff[q] = (unsigned)(bt * 81 + (hh + 1) * 9 + (ww + 1) - 10) * 256 + swseg;
        // note: (hh+kh)*9+(ww+kw) with kh,kw in 0..2 == base(hh*9+ww) + kh*9+kw
    }
    unsigned boff[2];
    #pragma unroll
    for (int q = 0; q < 2; ++q)
        boff[q] = (unsigned)(n0 + q * 64 + srow) * 256 + swseg;

    // stage one-third of tile s into buf s%3. part 0: A rows 0-127,
    // part 1: A rows 128-255, part 2: B rows 0-127. 2 GLDS each.
    auto STAGE = [&](int s, int part) {
        int kk = s >> 2;
        int kh = kk / 3, kw = kk - kh * 3;
        unsigned c0 = (unsigned)((s & 3) << 6);
        int buf = s - (s / 3) * 3;
        char* base = smem + buf * 49152;
        if (part < 2) {
            unsigned so = (unsigned)(kh * 9 + kw) * 256 + c0;
            #pragma unroll
            for (int u = 0; u < 2; ++u) {
                int q = part * 2 + u;
                GLDS(xp + (size_t)(aoff[q] + so), base + q * 8192 + tid * 16);
            }
        } else {
            unsigned so = (unsigned)kk * (DD * 256) + c0;
            #pragma unroll
            for (int u = 0; u < 2; ++u)
                GLDS(wb + (size_t)(boff[u] + so), base + 32768 + u * 8192 + tid * 16);
        }
    };

    f32x4 acc[4][4];
    #pragma unroll
    for (int i = 0; i < 4; ++i)
        #pragma unroll
        for (int j = 0; j < 4; ++j) acc[i][j] = (f32x4){0.f, 0.f, 0.f, 0.f};

    int offk[2] = {((0 + qd) ^ swz) * 16, ((4 + qd) ^ swz) * 16};

    // prologue: stage tiles 0 and 1 (12 loads/thread), wait tile 0 only.
    STAGE(0, 0); STAGE(0, 1); STAGE(0, 2);
    STAGE(1, 0); STAGE(1, 1); STAGE(1, 2);
    asm volatile("s_waitcnt vmcnt(6)" ::: "memory");
    __builtin_amdgcn_s_barrier();

    #pragma unroll 1
    for (int s = 0; s < 36; ++s) {
        const char* Ab = smem + (s - (s / 3) * 3) * 49152;
        const char* Bb = Ab + 32768;
        bool more = s < 34;
        bf16x8 af[2][2], b0r[2][2], b1r[2][2];

        // ---- phase 0: read A-half0 + B-half0; stage s+2 part 0
        #pragma unroll
        for (int i = 0; i < 2; ++i)
            #pragma unroll
            for (int k2 = 0; k2 < 2; ++k2)
                af[i][k2] = *(const bf16x8*)(Ab + (wm * 64 + i * 16 + ln) * 128 + offk[k2]);
        #pragma unroll
        for (int j = 0; j < 2; ++j)
            #pragma unroll
            for (int k2 = 0; k2 < 2; ++k2)
                b0r[j][k2] = *(const bf16x8*)(Bb + (wn * 64 + j * 16 + ln) * 128 + offk[k2]);
        if (more) STAGE(s + 2, 0);
        __builtin_amdgcn_s_barrier();
        asm volatile("s_waitcnt lgkmcnt(0)" ::: "memory");
        __builtin_amdgcn_sched_barrier(0);
        __builtin_amdgcn_s_setprio(1);
        #pragma unroll
        for (int i = 0; i < 2; ++i)
            #pragma unroll
            for (int j = 0; j < 2; ++j)
                #pragma unroll
                for (int k2 = 0; k2 < 2; ++k2)
                    acc[i][j] = MFMA16(af[i][k2], b0r[j][k2], acc[i][j]);
        __builtin_amdgcn_s_setprio(0);

        // ---- phase 1: read B-half1; stage s+2 part 1
        #pragma unroll
        for (int j = 0; j < 2; ++j)
            #pragma unroll
            for (int k2 = 0; k2 < 2; ++k2)
                b1r[j][k2] = *(const bf16x8*)(Bb + (wn * 64 + (j + 2) * 16 + ln) * 128 + offk[k2]);
        if (more) STAGE(s + 2, 1);
        __builtin_amdgcn_s_barrier();
        asm volatile("s_waitcnt lgkmcnt(0)" ::: "memory");
        __builtin_amdgcn_sched_barrier(0);
        __builtin_amdgcn_s_setprio(1);
        #pragma unroll
        for (int i = 0; i < 2; ++i)
            #pragma unroll
            for (int j = 0; j < 2; ++j)
                #pragma unroll
                for (int k2 = 0; k2 < 2; ++k2)
                    acc[i][j + 2] = MFMA16(af[i][k2], b1r[j][k2], acc[i][j + 2]);
        __builtin_amdgcn_s_setprio(0);

        // ---- phase 2: read A-half1 (overwrite af); stage s+2 part 2
        #pragma unroll
        for (int i = 0; i < 2; ++i)
            #pragma unroll
            for (int k2 = 0; k2 < 2; ++k2)
                af[i][k2] = *(const bf16x8*)(Ab + (wm * 64 + (i + 2) * 16 + ln) * 128 + offk[k2]);
        if (more) STAGE(s + 2, 2);
        __builtin_amdgcn_s_barrier();
        asm volatile("s_waitcnt lgkmcnt(0)" ::: "memory");
        __builtin_amdgcn_sched_barrier(0);
        __builtin_amdgcn_s_setprio(1);
        #pragma unroll
        for (int i = 0; i < 2; ++i)
            #pragma unroll
            for (int j = 0; j < 2; ++j)
                #pragma unroll
                for (int k2 = 0; k2 < 2; ++k2)
                    acc[i + 2][j] = MFMA16(af[i][k2], b0r[j][k2], acc[i + 2][j]);
        __builtin_amdgcn_s_setprio(0);

        // ---- phase 3: no reads
        __builtin_amdgcn_s_barrier();
        __builtin_amdgcn_s_setprio(1);
        #pragma unroll
        for (int i = 0; i < 2; ++i)
            #pragma unroll
            for (int j = 0; j < 2; ++j)
                #pragma unroll
                for (int k2 = 0; k2 < 2; ++k2)
                    acc[i + 2][j + 2] = MFMA16(af[i][k2], b1r[j][k2], acc[i + 2][j + 2]);
        __builtin_amdgcn_s_setprio(0);

        // ---- end of step: tile s+1 must be resident; s+2 stays in flight
        if (more) asm volatile("s_waitcnt vmcnt(6)" ::: "memory");
        else      asm volatile("s_waitcnt vmcnt(0)" ::: "memory");
        __builtin_amdgcn_s_barrier();
    }

    float swr[4], cbr[4];
    #pragma unroll
    for (int j = 0; j < 4; ++j) {
        int n = n0 + wn * 64 + j * 16 + ln;
        swr[j] = scorew[n];
        cbr[j] = convb[n];
    }
    float* dst = pl + (size_t)(nblk * 2 + wn) * TOTAL;
    #pragma unroll
    for (int i = 0; i < 4; ++i) {
        #pragma unroll
        for (int r = 0; r < 4; ++r) {
            float v = 0.f;
            #pragma unroll
            for (int j = 0; j < 4; ++j) {
                float h1 = acc[i][j][r] + cbr[j];
                h1 = h1 > 0.f ? h1 : 0.f;
                v = fmaf(swr[j], h1, v);
            }
            v += __shfl_xor(v, 1);
            v += __shfl_xor(v, 2);
            v += __shfl_xor(v, 4);
            v += __shfl_xor(v, 8);
            if (ln == 0)
                dst[m0 + wm * 64 + i * 16 + qd * 4 + r] = v;
        }
    }
}

// ---------------- K6: slot-sum + BCE + grid reduction (last block) ----------
__global__ __launch_bounds__(256) void k_bce(
        const float* __restrict__ pl, const float* __restrict__ cam,
        const float* __restrict__ sb, float* __restrict__ part,
        int* __restrict__ counter, float* __restrict__ out) {
    __shared__ float sbuf[256];
    __shared__ int isLast;
    int tid = threadIdx.x;
    int m = blockIdx.x * 256 + tid;
    float l = sb[0];
    #pragma unroll
    for (int s = 0; s < 8; ++s) l += pl[(size_t)s * TOTAL + m];
    float y = cam[m];
    float v = fmaxf(l, 0.f) - l * y + log1pf(expf(-fabsf(l)));
    sbuf[tid] = v; __syncthreads();
    for (int k = 128; k > 0; k >>= 1) {
        if (tid < k) sbuf[tid] += sbuf[tid + k];
        __syncthreads();
    }
    if (tid == 0) {
        part[blockIdx.x] = sbuf[0];
        __threadfence();
        int d = atomicAdd(counter, 1);
        isLast = (d == 391);
    }
    __syncthreads();
    if (isLast) {
        float s = 0.f;
        for (int i = tid; i < 392; i += 256) s += part[i];
        sbuf[tid] = s; __syncthreads();
        for (int k = 128; k > 0; k >>= 1) {
            if (tid < k) sbuf[tid] += sbuf[tid + k];
            __syncthreads();
        }
        if (tid == 0) out[0] = sbuf[0] * (1.0f / (float)TOTAL);
    }
}

extern "C" void kernel_launch(void* const* d_in, const int* in_sizes, int n_in,
                              void* d_out, int out_size, void* d_ws, size_t ws_size,
                              hipStream_t stream) {
    const float* x   = (const float*)d_in[0];
    const float* pv  = (const float*)d_in[1];
    const float* pn  = (const float*)d_in[2];
    const float* wpv = (const float*)d_in[3];
    const float* wpn = (const float*)d_in[4];
    const float* cw  = (const float*)d_in[5];
    const float* cb  = (const float*)d_in[6];
    const float* sw  = (const float*)d_in[7];
    const float* sb  = (const float*)d_in[8];

    char* w8 = (char*)d_ws;
    __hip_bfloat16* xp  = (__hip_bfloat16*)w8;                  // 84,934,656 B
    __hip_bfloat16* wb  = (__hip_bfloat16*)(w8 + 84934656);     //  2,359,296 B
    float* pl      = (float*)(w8 + 87293952);                   //  3,211,264 B
    float* cam     = (float*)(w8 + 90505216);                   //    401,408 B
    float* part    = (float*)(w8 + 90906624);                   //      1,568 B
    int*   counter = (int*)(w8 + 90908192);                     //          4 B

    k_trcam<<<64 + 1024, 256, 0, stream>>>(x, xp, cw, wb, pv, pn, wpv, wpn,
                                           cam, counter);
    k_gemm8<<<1568, 512, 0, stream>>>(xp, wb, cb, sw, pl);
    k_bce<<<392, 256, 0, stream>>>(pl, cam, sb, part, counter, (float*)d_out);
}